// Round 9
// baseline (122.250 us; speedup 1.0000x reference)
//
#include <hip/hip_runtime.h>
#include <math.h>

#define NCLS 9
#define DIM 768
#define NPIX 65536   // 4 * 128 * 128

// ---- workspace layout (bytes), no memset needed ----
#define OFF_LAB     ((size_t)0)        // uchar[65536]          = 65536
#define OFF_HIST    ((size_t)65536)    // int[256*9]            = 9216   -> 74752
#define OFF_SUMS    ((size_t)74752)    // float[9*768]          = 27648  -> 102400
#define OFF_SSQP    ((size_t)102400)   // float[256*9]          = 9216   -> 111616
#define OFF_LOSS    ((size_t)111616)   // float[4]  (zeroed by k0)
#define OFF_DONE    ((size_t)111632)   // uint[4]   (zeroed by k0: [0]=grid barrier, [1]=final ticket)
// total ~112 KB

__device__ __forceinline__ float waveReduceSum(float v) {
#pragma unroll
  for (int off = 32; off > 0; off >>= 1) v += __shfl_down(v, off, 64);
  return v;
}

// K0: downsample labels -> uchar lab[n]; per-block histogram -> hist[block][9];
// block 0 zero-inits lossacc/done for the mega kernel.
__global__ void k0_lab(const int* __restrict__ label, unsigned char* __restrict__ lab,
                       int* __restrict__ hist, float* __restrict__ lossacc,
                       unsigned int* __restrict__ done) {
  __shared__ int h[NCLS];
  int tid = threadIdx.x;
  if (tid < NCLS) h[tid] = 0;
  __syncthreads();
  int n = blockIdx.x * 256 + tid;
  int b = n >> 14, r = (n >> 7) & 127, cc = n & 127;
  int c = label[b * 262144 + r * 2048 + cc * 4];
  lab[n] = (unsigned char)c;
  atomicAdd(&h[c], 1);
  if (blockIdx.x == 0) {
    if (tid == 16) lossacc[0] = 0.f;
    else if (tid == 17) done[0] = 0u;
    else if (tid == 18) done[1] = 0u;
  }
  __syncthreads();
  if (tid < NCLS) hist[blockIdx.x * NCLS + tid] = h[tid];
}

// K1: per-class segment sums. One block per feature dim d. Pure streaming — NO
// fences/tickets (R2: agent-scope fence per block = 5x slowdown). This kernel
// pays the hidden L3 dirty-poison writeback tax (~200MB) on top of its 204MB
// read; it is the true ~55-60us floor of the pipeline.
__global__ void k1_segsum(const float4* __restrict__ feat4, const uchar4* __restrict__ lab4,
                          float* __restrict__ sums) {
  int d = blockIdx.x;
  int tid = threadIdx.x;
  float acc[NCLS];
#pragma unroll
  for (int k = 0; k < NCLS; ++k) acc[k] = 0.f;
  for (int b = 0; b < 4; ++b) {
    const float4* fp = feat4 + (size_t)(b * DIM + d) * 4096;
    const uchar4* lp = lab4 + b * 4096;
#pragma unroll 4
    for (int i = 0; i < 16; ++i) {
      int p = tid + i * 256;
      float4 f = fp[p];
      uchar4 l = lp[p];
      int lx = l.x, ly = l.y, lz = l.z, lw = l.w;
#pragma unroll
      for (int k = 0; k < NCLS; ++k) {
        acc[k] += (lx == k) ? f.x : 0.f;
        acc[k] += (ly == k) ? f.y : 0.f;
        acc[k] += (lz == k) ? f.z : 0.f;
        acc[k] += (lw == k) ? f.w : 0.f;
      }
    }
  }
  __shared__ float red[4][NCLS];
#pragma unroll
  for (int k = 0; k < NCLS; ++k) acc[k] = waveReduceSum(acc[k]);
  int lane = tid & 63, w = tid >> 6;
  if (lane == 0) {
#pragma unroll
    for (int k = 0; k < NCLS; ++k) red[w][k] = acc[k];
  }
  __syncthreads();
  if (tid < NCLS)
    sums[tid * DIM + d] = red[0][tid] + red[1][tid] + red[2][tid] + red[3][tid];
}

// MEGA (k2+k3+k4+k5): per-block proto prologue (R1-verified), R1's 98.6us k3
// main loop (4 dim-quarters x 256px, LDS plain-write combine), logits kept IN
// REGISTERS (no global round-trip), block ssq partials -> global (agent-scope
// atomic stores), manual grid barrier (tid==0-only fence+ticket+spin: one
// fence per BLOCK, not R2's per-thread fence storm), then per-pixel loss from
// registers + done-ticket finalize. All 256 blocks co-resident: 16 waves/block,
// launch_bounds(1024,4) caps VGPR at 128 -> 1 block/CU guaranteed.
__global__ void __launch_bounds__(1024, 4) k3_mega(
    const float* __restrict__ sums, const int* __restrict__ hist,
    const float* __restrict__ proto, const float* __restrict__ feat,
    const unsigned char* __restrict__ lab, float* __restrict__ ssqpart,
    float* __restrict__ lossacc, unsigned int* __restrict__ done,
    float* __restrict__ out) {
  __shared__ float pl[DIM * 12];  // 36864 B: protoT, then 3x [256][9] combine regions
  __shared__ float cpart[32][NCLS];
  __shared__ float cnt[NCLS];
  __shared__ float red12[12][NCLS];
  __shared__ float invn[NCLS];
  __shared__ float red4[4][NCLS];
  __shared__ float scale_s[NCLS];
  __shared__ float lred[4];
  int tid = threadIdx.x;

  // ---- prologue: counts from per-block hist ----
  if (tid < 288) {
    int c = tid % NCLS, g = tid / NCLS;  // g in 0..31
    int s = 0;
#pragma unroll
    for (int j = 0; j < 8; ++j) s += hist[(g * 8 + j) * NCLS + c];
    cpart[g][c] = (float)s;
  }
  __syncthreads();
  if (tid < NCLS) {
    float s = 0.f;
#pragma unroll
    for (int g = 0; g < 32; ++g) s += cpart[g][tid];
    cnt[tid] = s;
  }
  __syncthreads();

  // ---- prologue: protos = l2norm(0.99*mean + 0.01*proto) -> pl[d*12 + c] ----
  {
    float v[NCLS];
    if (tid < DIM) {
#pragma unroll
      for (int c = 0; c < NCLS; ++c)
        v[c] = 0.99f * (sums[c * DIM + tid] / cnt[c]) + 0.01f * proto[c * DIM + tid];
      int lane = tid & 63, w = tid >> 6;  // w in 0..11
#pragma unroll
      for (int c = 0; c < NCLS; ++c) {
        float q = waveReduceSum(v[c] * v[c]);
        if (lane == 0) red12[w][c] = q;
      }
    }
    __syncthreads();
    if (tid < NCLS) {
      float t = 0.f;
#pragma unroll
      for (int w2 = 0; w2 < 12; ++w2) t += red12[w2][tid];
      invn[tid] = 1.f / fmaxf(sqrtf(t), 1e-12f);
    }
    __syncthreads();
    if (tid < DIM) {
#pragma unroll
      for (int c = 0; c < NCLS; ++c) pl[tid * 12 + c] = v[c] * invn[c];
    }
    __syncthreads();
  }

  // ---- main: split-K logits (R1's 98.6us form). s = dim-quarter, p = pixel ----
  int s = tid >> 8, p = tid & 255;
  int n = blockIdx.x * 256 + p;
  int b = n >> 14, pp = n & 16383;
  const float* fp = feat + ((size_t)(b * DIM + s * 192)) * 16384 + pp;
  float a0 = 0, a1 = 0, a2 = 0, a3 = 0, a4 = 0, a5 = 0, a6 = 0, a7 = 0, a8 = 0;
#pragma unroll 4
  for (int dd = 0; dd < 192; ++dd) {
    float f = fp[(size_t)dd * 16384];
    const float4* pr = (const float4*)&pl[(s * 192 + dd) * 12];
    float4 q0 = pr[0];
    float4 q1 = pr[1];
    float q8 = pl[(s * 192 + dd) * 12 + 8];
    a0 += q0.x * f; a1 += q0.y * f; a2 += q0.z * f; a3 += q0.w * f;
    a4 += q1.x * f; a5 += q1.y * f; a6 += q1.z * f; a7 += q1.w * f;
    a8 += q8 * f;
  }
  __syncthreads();  // proto reads done; pl reusable as combine buffer
  if (s > 0) {
    float* rp = pl + (size_t)(s - 1) * 2304 + p * 9;
    rp[0] = a0; rp[1] = a1; rp[2] = a2; rp[3] = a3; rp[4] = a4;
    rp[5] = a5; rp[6] = a6; rp[7] = a7; rp[8] = a8;
  }
  __syncthreads();
  if (s == 0) {
#pragma unroll
    for (int q = 0; q < 3; ++q) {
      const float* rp = pl + (size_t)q * 2304 + p * 9;
      a0 += rp[0]; a1 += rp[1]; a2 += rp[2]; a3 += rp[3]; a4 += rp[4];
      a5 += rp[5]; a6 += rp[6]; a7 += rp[7]; a8 += rp[8];
    }
    // ssq wave-reduce (waves 0-3 hold s==0)
    float ss[NCLS] = {a0 * a0, a1 * a1, a2 * a2, a3 * a3, a4 * a4,
                      a5 * a5, a6 * a6, a7 * a7, a8 * a8};
#pragma unroll
    for (int c = 0; c < NCLS; ++c) ss[c] = waveReduceSum(ss[c]);
    int lane = tid & 63, w = tid >> 6;
    if (lane == 0) {
#pragma unroll
      for (int c = 0; c < NCLS; ++c) red4[w][c] = ss[c];
    }
  }
  __syncthreads();
  if (tid < NCLS) {
    float t = red4[0][tid] + red4[1][tid] + red4[2][tid] + red4[3][tid];
    __hip_atomic_store(&ssqpart[blockIdx.x * NCLS + tid], t, __ATOMIC_RELAXED,
                       __HIP_MEMORY_SCOPE_AGENT);
  }
  __syncthreads();

  // ---- manual grid barrier: single thread per block fences/spins ----
  if (tid == 0) {
    __threadfence();                 // release ssqpart stores
    atomicAdd(&done[0], 1u);
    while (__hip_atomic_load(&done[0], __ATOMIC_ACQUIRE, __HIP_MEMORY_SCOPE_AGENT) <
           gridDim.x) {
      __builtin_amdgcn_s_sleep(2);
    }
  }
  __syncthreads();

  // ---- phase B: reduce ssqpart -> scale ----
  if (tid < 288) {
    int c = tid % NCLS, g = tid / NCLS;  // g in 0..31
    float t = 0.f;
#pragma unroll
    for (int j = 0; j < 8; ++j)
      t += __hip_atomic_load(&ssqpart[(g * 8 + j) * NCLS + c], __ATOMIC_RELAXED,
                             __HIP_MEMORY_SCOPE_AGENT);
    cpart[g][c] = t;
  }
  __syncthreads();
  if (tid < NCLS) {
    float t = 0.f;
#pragma unroll
    for (int g = 0; g < 32; ++g) t += cpart[g][tid];
    scale_s[tid] = 10.f / fmaxf(sqrtf(t), 1e-12f);
  }
  __syncthreads();

  // ---- phase B: per-pixel loss from registered logits ----
  if (s == 0) {
    int l = lab[n];
    int lc = (l == 7) ? 6 : l;
    float av[NCLS] = {a0, a1, a2, a3, a4, a5, a6, a7, a8};
    float sumE = 0.f, picked = 0.f;
#pragma unroll
    for (int c = 0; c < NCLS; ++c) {
      float pf = (c == 2) ? ((lc == 2) ? 1.f : 0.f) : av[c] * scale_s[c];
      sumE += __expf(pf);
      picked += (c == lc) ? pf : 0.f;
    }
    float lsum = __logf(sumE) - picked;
    lsum = waveReduceSum(lsum);
    int lane = tid & 63, w = tid >> 6;
    if (lane == 0) lred[w] = lsum;
  }
  __syncthreads();
  if (tid == 0) {
    atomicAdd(lossacc, lred[0] + lred[1] + lred[2] + lred[3]);
    __threadfence();
    unsigned int ticket = atomicAdd(&done[1], 1u);
    if (ticket == gridDim.x - 1) {
      __threadfence();
      float total = __hip_atomic_load(lossacc, __ATOMIC_ACQUIRE, __HIP_MEMORY_SCOPE_AGENT);
      out[0] = total * (1.f / (float)NPIX);
    }
  }
}

extern "C" void kernel_launch(void* const* d_in, const int* in_sizes, int n_in,
                              void* d_out, int out_size, void* d_ws, size_t ws_size,
                              hipStream_t stream) {
  // inputs: 0=cls_score (unused), 1=label, 2=gt_lucas (unused), 3=features, 4=prototypes
  const int* label = (const int*)d_in[1];
  const float* feat = (const float*)d_in[3];
  const float* proto = (const float*)d_in[4];
  char* ws = (char*)d_ws;
  unsigned char* lab = (unsigned char*)(ws + OFF_LAB);
  int* hist = (int*)(ws + OFF_HIST);
  float* sums = (float*)(ws + OFF_SUMS);
  float* ssqpart = (float*)(ws + OFF_SSQP);
  float* lossacc = (float*)(ws + OFF_LOSS);
  unsigned int* done = (unsigned int*)(ws + OFF_DONE);

  k0_lab<<<NPIX / 256, 256, 0, stream>>>(label, lab, hist, lossacc, done);
  k1_segsum<<<DIM, 256, 0, stream>>>((const float4*)feat, (const uchar4*)lab, sums);
  k3_mega<<<NPIX / 256, 1024, 0, stream>>>(sums, hist, proto, feat, lab, ssqpart,
                                           lossacc, done, (float*)d_out);
}